// Round 11
// baseline (195.602 us; speedup 1.0000x reference)
//
#include <hip/hip_runtime.h>
#include <stdint.h>

// ---------------------------------------------------------------------------
// MultiScaleGRU fused pipeline (MI355X / gfx950)
//
//   gi = (A @ C) @ w_ih^T + b_ih      A: [16384,4096] fp32 (attention_weights)
//   gh = h @ w_hh^T + b_hh            h: repeat(C[:16], 4)  -> [64,256]
//   r,z = sigmoid(gi_rz + gh_rz); n = tanh(gi_n + r*gh_n)
//   h_new = (1-z)*n + z*h ; out[o,b,:] = mean_j h_new[b, 4o+j, :]
//
// Numerics (passing, absmax 0.0156): single fp16 path, A centered (a-0.5)
// with exact fp32 csW folded into stage-2 bias. K-order unchanged.
//
// R11 stage1: R6..R10 all landed 150-190us independent of traffic volume ->
// latency-bound at shallow concurrency. Fixes: (1) wave-tile 64x64 (mi=ni=4,
// 0.5 LDS-reads/MFMA vs 0.75) -> 4 waves cover BM=64 x BN=256; (2) grid 256,
// per-CU B bytes halved to 2MB, Ct L2-resident under NT-A; (3) honest
// pipeline: B dbuf staged AFTER the compute barrier, vmcnt(0) only at
// top-of-iter (everything waited has >=1 iter ~1600cy of flight >= 900cy L3
// latency); A prefetched 2 deep into named even/odd register sets.
// Iter wall = A-HBM bound ~1600cy -> stage1 ~ 43us ~ 256MB HBM floor.
// ---------------------------------------------------------------------------

typedef _Float16 half8 __attribute__((ext_vector_type(8)));
typedef float f32x4 __attribute__((ext_vector_type(4)));

// workspace layout (bytes)
#define WS_CT   0u          // Ct  : fp16 [256][4096] swz   (2 MB)
#define WS_WP   2097152u    // Wp  : fp16 [768][256]  swz   (384 KB)
#define WS_GH   2490368u    // GH  : f32  [64][768]         (192 KB)
#define WS_CSP  2686976u    // csum partials: f32 [64][256] (64 KB)
#define WS_CS   2752512u    // cs  : f32 [256]              (1 KB)
#define WS_CSW  2753536u    // csW : f32 [768]              (3 KB)
#define WS_X    2756608u    // X   : fp16 [16384][256] swz  (8 MB)
// total 11,145,216 bytes

static __device__ __forceinline__ _Float16 f2h(float x) {
  return (_Float16)x;  // v_cvt_f16_f32, RNE
}
static __device__ __forceinline__ void gload16(const void* g, void* lds) {
  // async global->LDS, 16B/lane; LDS dest = wave-uniform base + lane*16
  __builtin_amdgcn_global_load_lds(
      (const __attribute__((address_space(1))) unsigned int*)g,
      (__attribute__((address_space(3))) unsigned int*)lds, 16, 0, 0);
}
static __device__ __forceinline__ float sigmf(float x) {
  float e = __expf(-fabsf(x));
  float p = 1.f / (1.f + e);
  return x >= 0.f ? p : 1.f - p;
}
static __device__ __forceinline__ float tanhf2(float x) {
  float e = __expf(-2.f * fabsf(x));
  float t = 1.f - 2.f * e / (1.f + e);
  return x >= 0.f ? t : -t;
}

// ---------------------------------------------------------------------------
// prep 1: C[4096][256] f32 -> Ct[256(h)][4096(f)] fp16, swizzled
__global__ void __launch_bounds__(256) k_transC(const float* __restrict__ C,
                                                _Float16* __restrict__ Ct) {
  __shared__ float sT[64][65];
  const int f0 = blockIdx.x * 64, h0 = blockIdx.y * 64;
  const int t = threadIdx.x;
#pragma unroll
  for (int i = 0; i < 4; ++i) {
    int fl = t + 256 * i;
    int r = fl >> 4, c4 = fl & 15;
    float4 v = *(const float4*)(C + (size_t)(f0 + r) * 256 + h0 + c4 * 4);
    sT[r][c4 * 4 + 0] = v.x; sT[r][c4 * 4 + 1] = v.y;
    sT[r][c4 * 4 + 2] = v.z; sT[r][c4 * 4 + 3] = v.w;
  }
  __syncthreads();
#pragma unroll
  for (int i = 0; i < 2; ++i) {
    int q = t + 256 * i;         // 512 chunks of 8 fp16
    int hr = q >> 3, j = q & 7;  // out row (h), f-chunk within 64
    int h = h0 + hr;
    union { half8 v; _Float16 u[8]; } pk;
#pragma unroll
    for (int u = 0; u < 8; ++u) pk.u[u] = f2h(sT[j * 8 + u][hr]);
    size_t off = (size_t)h * 8192 + (size_t)f0 * 2 + (size_t)((j ^ (h & 7)) << 4);
    *(half8*)((char*)Ct + off) = pk.v;
  }
}

// prep 1b: colsum (deterministic 2-step tree) -> cs[h] = 0.5*sum_f C[f][h]
__global__ void __launch_bounds__(256) k_csum(const float* __restrict__ C,
                                              float* __restrict__ part) {
  const int b = blockIdx.x, t = threadIdx.x;  // grid 64, 64 rows each
  float s = 0.f;
  for (int k = 0; k < 64; ++k) s += C[(size_t)(b * 64 + k) * 256 + t];
  part[b * 256 + t] = s;
}
__global__ void __launch_bounds__(256) k_csum2(const float* __restrict__ part,
                                               float* __restrict__ csum) {
  const int t = threadIdx.x;
  float s = 0.f;
#pragma unroll
  for (int b = 0; b < 64; ++b) s += part[b * 256 + t];
  csum[t] = 0.5f * s;
}
// prep 1c: csW[n] = sum_h cs[h]*w_ih[n][h]  (exact fp32; wave-per-n dot)
__global__ void __launch_bounds__(256) k_csumW(const float* __restrict__ w_ih,
                                               const float* __restrict__ cs,
                                               float* __restrict__ csW) {
  const int wv = threadIdx.x >> 6, l = threadIdx.x & 63;
  const int n = blockIdx.x * 4 + wv;  // grid 192 -> n 0..767
  float4 w = *(const float4*)(w_ih + (size_t)n * 256 + l * 4);
  float4 c = *(const float4*)(cs + l * 4);
  float s = w.x * c.x + w.y * c.y + w.z * c.z + w.w * c.w;
#pragma unroll
  for (int off = 32; off; off >>= 1) s += __shfl_down(s, off, 64);
  if (l == 0) csW[n] = s;
}

// prep 2: w_ih[768][256] f32 -> Wp[n'=3h+g][256] fp16, swizzled
__global__ void __launch_bounds__(256) k_prepWp(const float* __restrict__ w_ih,
                                                _Float16* __restrict__ Wp) {
  int q = blockIdx.x * 256 + threadIdx.x;  // 24576 chunks
  int row = q >> 5, c = q & 31;
  int seg = c >> 3, j = c & 7;
  int srow = (row % 3) * 256 + row / 3;    // gate-interleave permutation
  const float* src = w_ih + (size_t)srow * 256 + c * 8;
  union { half8 v; _Float16 u[8]; } pk;
#pragma unroll
  for (int u = 0; u < 8; ++u) pk.u[u] = f2h(src[u]);
  size_t off = (size_t)row * 512 + seg * 128 + ((j ^ (row & 7)) << 4);
  *(half8*)((char*)Wp + off) = pk.v;
}

// prep 3: GH[64][768] = h @ w_hh^T + b_hh   (exact fp32)
__global__ void __launch_bounds__(256) k_gh(const float* __restrict__ centers,
                                            const float* __restrict__ w_hh,
                                            const float* __restrict__ b_hh,
                                            float* __restrict__ GH) {
  __shared__ __align__(16) float sH[256];
  const int s = blockIdx.x, t = threadIdx.x;
  sH[t] = centers[(size_t)(s >> 2) * 256 + t];
  __syncthreads();
#pragma unroll
  for (int e = 0; e < 3; ++e) {
    int n = e * 256 + t;
    float accv = b_hh[n];
    const float4* w = (const float4*)(w_hh + (size_t)n * 256);
#pragma unroll 8
    for (int k = 0; k < 64; ++k) {
      float4 v = w[k];
      float4 hh = *(const float4*)&sH[k * 4];
      accv += v.x * hh.x + v.y * hh.y + v.z * hh.z + v.w * hh.w;
    }
    GH[(size_t)s * 768 + n] = accv;
  }
}

// ---------------------------------------------------------------------------
// stage 1: X = (A-0.5) @ C   (fp16 MFMA, fp32 accum).
// BM=64, BN=256, BK=64. grid 256 (1 block/CU), 256 thr = 4 waves 1Mx4N,
// wave tile 64x64 (acc 4x4 f32x4). LDS 80KB: sA dbuf 2x8KB, sB dbuf 2x32KB.
__global__ void __launch_bounds__(256, 1) k_stage1(const float* __restrict__ A,
                                                   const _Float16* __restrict__ Ct,
                                                   _Float16* __restrict__ X) {
  __shared__ __align__(16) _Float16 sA0[64 * 64];   //  8 KB
  __shared__ __align__(16) _Float16 sA1[64 * 64];   //  8 KB
  __shared__ __align__(16) _Float16 sB0[256 * 64];  // 32 KB
  __shared__ __align__(16) _Float16 sB1[256 * 64];  // 32 KB
  const int t = threadIdx.x;
  const int wid = t >> 6, l = t & 63;
  const int lr = l & 15, lk = l >> 4;
  const int m0 = blockIdx.x * 64;

  f32x4 acc[4][4];
#pragma unroll
  for (int i = 0; i < 4; ++i)
#pragma unroll
    for (int j = 0; j < 4; ++j) acc[i][j] = (f32x4){0.f, 0.f, 0.f, 0.f};

  // A staging: thread t -> row ar (0..63), 16-float quarter ac4 (0..3)
  const int ar = t >> 2, ac4 = t & 3;
  const float* aptr = A + (size_t)(m0 + ar) * 4096 + ac4 * 16;
  const int saw0 = ar * 128 + (((2 * ac4 + 0) ^ (ar & 7)) << 4);
  const int saw1 = ar * 128 + (((2 * ac4 + 1) ^ (ar & 7)) << 4);

  // B staging: flat = t + 256*i -> row brow+32i, chunk bch (src pre-swizzled)
  const int brow = t >> 3, bch = t & 7;

  // ---- prologue: B(0)->sB0; A(0)->aEv, A(1)->aOd (NT, 2-deep)
#pragma unroll
  for (int i = 0; i < 8; ++i)
    gload16(Ct + (size_t)(brow + 32 * i) * 4096 + bch * 8,
            (char*)sB0 + (wid * 64 + 256 * i) * 16);
  f32x4 aEv[4], aOd[4];
#pragma unroll
  for (int j = 0; j < 4; ++j)
    aEv[j] = __builtin_nontemporal_load((const f32x4*)(aptr + j * 4));
#pragma unroll
  for (int j = 0; j < 4; ++j)
    aOd[j] = __builtin_nontemporal_load((const f32x4*)(aptr + 64 + j * 4));

  // one pipeline iteration; all buffer/regset choices are compile-time
  auto ITER = [&](int kk, f32x4* areg, _Float16* sAc, _Float16* sBc,
                  _Float16* sBn) {
    // everything this waits on was issued >=1 full iter (~1600cy) ago
    asm volatile("s_waitcnt vmcnt(0)" ::: "memory");
    {  // ds_write A(kk) (centered, RNE cvt) -> sAc
      union { half8 v; _Float16 u[8]; } w0, w1;
      w0.u[0] = f2h(areg[0].x - 0.5f); w0.u[1] = f2h(areg[0].y - 0.5f);
      w0.u[2] = f2h(areg[0].z - 0.5f); w0.u[3] = f2h(areg[0].w - 0.5f);
      w0.u[4] = f2h(areg[1].x - 0.5f); w0.u[5] = f2h(areg[1].y - 0.5f);
      w0.u[6] = f2h(areg[1].z - 0.5f); w0.u[7] = f2h(areg[1].w - 0.5f);
      w1.u[0] = f2h(areg[2].x - 0.5f); w1.u[1] = f2h(areg[2].y - 0.5f);
      w1.u[2] = f2h(areg[2].z - 0.5f); w1.u[3] = f2h(areg[2].w - 0.5f);
      w1.u[4] = f2h(areg[3].x - 0.5f); w1.u[5] = f2h(areg[3].y - 0.5f);
      w1.u[6] = f2h(areg[3].z - 0.5f); w1.u[7] = f2h(areg[3].w - 0.5f);
      *(half8*)((char*)sAc + saw0) = w0.v;
      *(half8*)((char*)sAc + saw1) = w1.v;
    }
    if (kk <= 61) {  // A(kk+2) -> same regset (freed by the ds_write)
      const float* ap = aptr + (kk + 2) * 64;
#pragma unroll
      for (int j = 0; j < 4; ++j)
        areg[j] = __builtin_nontemporal_load((const f32x4*)(ap + j * 4));
    }
    if (kk <= 62) {  // B(kk+1) -> other buffer (readers done at prev barrier)
#pragma unroll
      for (int i = 0; i < 8; ++i)
        gload16(Ct + (size_t)(brow + 32 * i) * 4096 + (size_t)(kk + 1) * 64 + bch * 8,
                (char*)sBn + (wid * 64 + 256 * i) * 16);
    }
    asm volatile("s_waitcnt lgkmcnt(0)" ::: "memory");
    __builtin_amdgcn_s_barrier();
    asm volatile("" ::: "memory");
    // compute tile kk: wave tile 64x64, mi=ni=4
#pragma unroll
    for (int kc = 0; kc < 2; ++kc) {
      const int q = kc * 4 + lk;
      half8 af[4], bf[4];
#pragma unroll
      for (int mi = 0; mi < 4; ++mi) {
        int rl = mi * 16 + lr;
        af[mi] = *(const half8*)((const char*)sAc + rl * 128 + ((q ^ (rl & 7)) << 4));
      }
#pragma unroll
      for (int ni = 0; ni < 4; ++ni) {
        int rb = wid * 64 + ni * 16 + lr;
        bf[ni] = *(const half8*)((const char*)sBc + rb * 128 + ((q ^ (rb & 7)) << 4));
      }
#pragma unroll
      for (int mi = 0; mi < 4; ++mi)
#pragma unroll
        for (int ni = 0; ni < 4; ++ni)
          acc[mi][ni] = __builtin_amdgcn_mfma_f32_16x16x32_f16(af[mi], bf[ni], acc[mi][ni], 0, 0, 0);
    }
    asm volatile("" ::: "memory");
    __builtin_amdgcn_s_barrier();  // readers done before next iter's stage
    asm volatile("" ::: "memory");
  };

  for (int kx = 0; kx < 64; kx += 2) {
    ITER(kx + 0, aEv, sA0, sB0, sB1);
    ITER(kx + 1, aOd, sA1, sB1, sB0);
  }

  // epilogue: X -> fp16 (RNE), pre-swizzled storage
#pragma unroll
  for (int mi = 0; mi < 4; ++mi)
#pragma unroll
    for (int ni = 0; ni < 4; ++ni)
#pragma unroll
      for (int p = 0; p < 4; ++p) {
        int m = m0 + mi * 16 + lk * 4 + p;        // C/D: row=(lane>>4)*4+reg
        int col = wid * 64 + ni * 16 + lr;        //      col=lane&15
        size_t off = (size_t)m * 512 + ((col >> 6) << 7) +
                     ((((col >> 3) & 7) ^ (m & 7)) << 4) + ((col & 7) << 1);
        *(_Float16*)((char*)X + off) = f2h(acc[mi][ni][p]);
      }
}

// ---------------------------------------------------------------------------
// stage 2: GI = X@W (single fp16 pass) + (b_ih + csW) + fused GRU + mean.
// grid 256 (block = batch b), 256 thr, 4 waves 2Mx2N. X panel (32 KB)
// resident in LDS; W tiles (96x256 fp16, 48 KB) staged once per ntile.
// sC (epilogue) aliases the W buffer.
__global__ void __launch_bounds__(256) k_stage2(const _Float16* __restrict__ X,
                                                const _Float16* __restrict__ Wp,
                                                const float* __restrict__ GH,
                                                const float* __restrict__ centers,
                                                const float* __restrict__ b_ih,
                                                const float* __restrict__ csW,
                                                float* __restrict__ out) {
  __shared__ __align__(16) char smem[81920];   // 80 KB
  _Float16* sX = (_Float16*)smem;              // [64][256] fp16 swz : 32 KB
  char*     sW = smem + 32768;                 // [96][256] fp16 swz : 48 KB
  float*    sC = (float*)(smem + 32768);       // [64][100] f32 (aliases sW)
  const int t = threadIdx.x;
  const int wid = t >> 6, l = t & 63;
  const int lr = l & 15, lk = l >> 4;
  const int wm = wid >> 1, wn = wid & 1;
  const int b = blockIdx.x;

  // stage X panel: rows b*64 .. b*64+63 (raw 16B chunks, layout preserved)
#pragma unroll
  for (int i = 0; i < 8; ++i) {
    int flat = t + 256 * i;
    gload16((const char*)X + ((size_t)b * 64 + (flat >> 5)) * 512 +
                (size_t)(flat & 31) * 16,
            (char*)sX + (wid * 64 + 256 * i) * 16);
  }
  __syncthreads();

  for (int nt = 0; nt < 8; ++nt) {
    const int n0 = nt * 96;
    f32x4 acc[2][3];
#pragma unroll
    for (int i = 0; i < 2; ++i)
#pragma unroll
      for (int j = 0; j < 3; ++j) acc[i][j] = (f32x4){0.f, 0.f, 0.f, 0.f};

    // stage W tile 96 x 512B
#pragma unroll
    for (int i = 0; i < 12; ++i) {
      int flat = t + 256 * i;
      gload16((const char*)Wp + (size_t)(n0 + (flat >> 5)) * 512 +
                  (size_t)(flat & 31) * 16,
              sW + (wid * 64 + 256 * i) * 16);
    }
    __syncthreads();  // full drain: W visible
#pragma unroll
    for (int kc = 0; kc < 8; ++kc) {
      const int q = kc * 4 + lk;
      const int seg = (q >> 3) << 7, jj = q & 7;
      half8 af[2];
#pragma unroll
      for (int mi = 0; mi < 2; ++mi) {
        int rl = wm * 32 + mi * 16 + lr;
        af[mi] = *(const half8*)((const char*)sX + rl * 512 + seg + ((jj ^ (rl & 7)) << 4));
      }
#pragma unroll
      for (int ni = 0; ni < 3; ++ni) {
        int rw = wn * 48 + ni * 16 + lr;
        half8 bf = *(const half8*)(sW + rw * 512 + seg + ((jj ^ (rw & 7)) << 4));
#pragma unroll
        for (int mi = 0; mi < 2; ++mi)
          acc[mi][ni] = __builtin_amdgcn_mfma_f32_16x16x32_f16(af[mi], bf, acc[mi][ni], 0, 0, 0);
      }
    }
    __syncthreads();  // all sW reads done before sC alias write
    // acc -> sC (rows = slot s, cols = 3*hl + gate)
#pragma unroll
    for (int mi = 0; mi < 2; ++mi)
#pragma unroll
      for (int ni = 0; ni < 3; ++ni)
#pragma unroll
        for (int p = 0; p < 4; ++p) {
          int row = wm * 32 + mi * 16 + lk * 4 + p;
          int col = wn * 48 + ni * 16 + lr;
          sC[row * 100 + col] = acc[mi][ni][p];
        }
    __syncthreads();
    // fused GRU + level-mean: 16 o x 32 h = 512 items, 2 per thread
#pragma unroll
    for (int ii = 0; ii < 2; ++ii) {
      int item = t + 256 * ii;
      int hl = item & 31, o = item >> 5;
      int h = nt * 32 + hl;
      float hprev = centers[o * 256 + h];
      float bir = b_ih[h] + csW[h];
      float biz = b_ih[256 + h] + csW[256 + h];
      float bin = b_ih[512 + h] + csW[512 + h];
      float sum = 0.f;
#pragma unroll
      for (int j = 0; j < 4; ++j) {
        int s = 4 * o + j;
        float gir = sC[s * 100 + 3 * hl + 0] + bir;
        float giz = sC[s * 100 + 3 * hl + 1] + biz;
        float gin = sC[s * 100 + 3 * hl + 2] + bin;
        float rg = sigmf(gir + GH[s * 768 + h]);
        float zg = sigmf(giz + GH[s * 768 + 256 + h]);
        float ng = tanhf2(gin + rg * GH[s * 768 + 512 + h]);
        sum += (1.f - zg) * ng + zg * hprev;
      }
      out[(size_t)o * 65536 + (size_t)b * 256 + h] = 0.25f * sum;
    }
    __syncthreads();  // sC reads done before next ntile's sW stage (alias)
  }
}

// ---------------------------------------------------------------------------
extern "C" void kernel_launch(void* const* d_in, const int* in_sizes, int n_in,
                              void* d_out, int out_size, void* d_ws, size_t ws_size,
                              hipStream_t stream) {
  (void)in_sizes; (void)n_in; (void)out_size; (void)ws_size;
  const float* attn    = (const float*)d_in[0];  // [256][64][4096]
  const float* centers = (const float*)d_in[1];  // [4096][256]
  const float* w_ih    = (const float*)d_in[2];  // [768][256]
  const float* w_hh    = (const float*)d_in[3];  // [768][256]
  const float* b_ih    = (const float*)d_in[4];  // [768]
  const float* b_hh    = (const float*)d_in[5];  // [768]

  char* ws = (char*)d_ws;
  _Float16* Ct  = (_Float16*)(ws + WS_CT);
  _Float16* Wpp = (_Float16*)(ws + WS_WP);
  float*    GHp = (float*)(ws + WS_GH);
  float*    csp = (float*)(ws + WS_CSP);
  float*    cs  = (float*)(ws + WS_CS);
  float*    csW = (float*)(ws + WS_CSW);
  _Float16* X   = (_Float16*)(ws + WS_X);
  float* out = (float*)d_out;

  hipLaunchKernelGGL(k_transC, dim3(64, 4), dim3(256), 0, stream, centers, Ct);
  hipLaunchKernelGGL(k_csum, dim3(64), dim3(256), 0, stream, centers, csp);
  hipLaunchKernelGGL(k_csum2, dim3(1), dim3(256), 0, stream, csp, cs);
  hipLaunchKernelGGL(k_csumW, dim3(192), dim3(256), 0, stream, w_ih, cs, csW);
  hipLaunchKernelGGL(k_prepWp, dim3(96), dim3(256), 0, stream, w_ih, Wpp);
  hipLaunchKernelGGL(k_gh, dim3(64), dim3(256), 0, stream, centers, w_hh, b_hh, GHp);
  hipLaunchKernelGGL(k_stage1, dim3(256), dim3(256), 0, stream, attn, Ct, X);
  hipLaunchKernelGGL(k_stage2, dim3(256), dim3(256), 0, stream, X, Wpp, GHp, centers, b_ih, csW, out);
}

// Round 12
// 167.353 us; speedup vs baseline: 1.1688x; 1.1688x over previous
//
#include <hip/hip_runtime.h>
#include <stdint.h>

// ---------------------------------------------------------------------------
// MultiScaleGRU fused pipeline (MI355X / gfx950)
//
//   gi = (A @ C) @ w_ih^T + b_ih      A: [16384,4096] fp32 (attention_weights)
//   gh = h @ w_hh^T + b_hh            h: repeat(C[:16], 4)  -> [64,256]
//   r,z = sigmoid(gi_rz + gh_rz); n = tanh(gi_n + r*gh_n)
//   h_new = (1-z)*n + z*h ; out[o,b,:] = mean_j h_new[b, 4o+j, :]
//
// Numerics (passing, absmax 0.0156): single fp16 path, A centered (a-0.5)
// with exact fp32 csW folded into stage-2 bias. K-order unchanged.
//
// R12 stage1: COUNTED pipeline + TLP. R6-R11 all ~150us because the top-of-
// iter vmcnt(0) drained same/prev-iter issues after only ~1 compute phase of
// flight (< HBM/L3 delivery) with <=4 waves/CU to hide the stall. Now:
// BM=32, grid 512, 2 blocks/CU (72KB LDS); fixed per-iter issue order
// [B(k+1) x8 gload_lds, A(k+2) x2 NT] so top-of-iter FIFO is exactly
// B(k)[8],A(k+1)[2] -> s_waitcnt vmcnt(2) drains B(k) ONLY. One barrier
// per iter. vmcnt(0) only at the last iter. A's ds_write relies on the
// compiler's exact-count wait (vmcnt(10)) -> ~1.2 iters of A flight.
// ---------------------------------------------------------------------------

typedef _Float16 half8 __attribute__((ext_vector_type(8)));
typedef float f32x4 __attribute__((ext_vector_type(4)));

// workspace layout (bytes)
#define WS_CT   0u          // Ct  : fp16 [256][4096] swz   (2 MB)
#define WS_WP   2097152u    // Wp  : fp16 [768][256]  swz   (384 KB)
#define WS_GH   2490368u    // GH  : f32  [64][768]         (192 KB)
#define WS_CSP  2686976u    // csum partials: f32 [64][256] (64 KB)
#define WS_CS   2752512u    // cs  : f32 [256]              (1 KB)
#define WS_CSW  2753536u    // csW : f32 [768]              (3 KB)
#define WS_X    2756608u    // X   : fp16 [16384][256] swz  (8 MB)
// total 11,145,216 bytes

static __device__ __forceinline__ _Float16 f2h(float x) {
  return (_Float16)x;  // v_cvt_f16_f32, RNE
}
static __device__ __forceinline__ void gload16(const void* g, void* lds) {
  // async global->LDS, 16B/lane; LDS dest = wave-uniform base + lane*16
  __builtin_amdgcn_global_load_lds(
      (const __attribute__((address_space(1))) unsigned int*)g,
      (__attribute__((address_space(3))) unsigned int*)lds, 16, 0, 0);
}
static __device__ __forceinline__ float sigmf(float x) {
  float e = __expf(-fabsf(x));
  float p = 1.f / (1.f + e);
  return x >= 0.f ? p : 1.f - p;
}
static __device__ __forceinline__ float tanhf2(float x) {
  float e = __expf(-2.f * fabsf(x));
  float t = 1.f - 2.f * e / (1.f + e);
  return x >= 0.f ? t : -t;
}

// ---------------------------------------------------------------------------
// prep 1: C[4096][256] f32 -> Ct[256(h)][4096(f)] fp16, swizzled
__global__ void __launch_bounds__(256) k_transC(const float* __restrict__ C,
                                                _Float16* __restrict__ Ct) {
  __shared__ float sT[64][65];
  const int f0 = blockIdx.x * 64, h0 = blockIdx.y * 64;
  const int t = threadIdx.x;
#pragma unroll
  for (int i = 0; i < 4; ++i) {
    int fl = t + 256 * i;
    int r = fl >> 4, c4 = fl & 15;
    float4 v = *(const float4*)(C + (size_t)(f0 + r) * 256 + h0 + c4 * 4);
    sT[r][c4 * 4 + 0] = v.x; sT[r][c4 * 4 + 1] = v.y;
    sT[r][c4 * 4 + 2] = v.z; sT[r][c4 * 4 + 3] = v.w;
  }
  __syncthreads();
#pragma unroll
  for (int i = 0; i < 2; ++i) {
    int q = t + 256 * i;         // 512 chunks of 8 fp16
    int hr = q >> 3, j = q & 7;  // out row (h), f-chunk within 64
    int h = h0 + hr;
    union { half8 v; _Float16 u[8]; } pk;
#pragma unroll
    for (int u = 0; u < 8; ++u) pk.u[u] = f2h(sT[j * 8 + u][hr]);
    size_t off = (size_t)h * 8192 + (size_t)f0 * 2 + (size_t)((j ^ (h & 7)) << 4);
    *(half8*)((char*)Ct + off) = pk.v;
  }
}

// prep 1b: colsum (deterministic 2-step tree) -> cs[h] = 0.5*sum_f C[f][h]
__global__ void __launch_bounds__(256) k_csum(const float* __restrict__ C,
                                              float* __restrict__ part) {
  const int b = blockIdx.x, t = threadIdx.x;  // grid 64, 64 rows each
  float s = 0.f;
  for (int k = 0; k < 64; ++k) s += C[(size_t)(b * 64 + k) * 256 + t];
  part[b * 256 + t] = s;
}
__global__ void __launch_bounds__(256) k_csum2(const float* __restrict__ part,
                                               float* __restrict__ csum) {
  const int t = threadIdx.x;
  float s = 0.f;
#pragma unroll
  for (int b = 0; b < 64; ++b) s += part[b * 256 + t];
  csum[t] = 0.5f * s;
}
// prep 1c: csW[n] = sum_h cs[h]*w_ih[n][h]  (exact fp32; wave-per-n dot)
__global__ void __launch_bounds__(256) k_csumW(const float* __restrict__ w_ih,
                                               const float* __restrict__ cs,
                                               float* __restrict__ csW) {
  const int wv = threadIdx.x >> 6, l = threadIdx.x & 63;
  const int n = blockIdx.x * 4 + wv;  // grid 192 -> n 0..767
  float4 w = *(const float4*)(w_ih + (size_t)n * 256 + l * 4);
  float4 c = *(const float4*)(cs + l * 4);
  float s = w.x * c.x + w.y * c.y + w.z * c.z + w.w * c.w;
#pragma unroll
  for (int off = 32; off; off >>= 1) s += __shfl_down(s, off, 64);
  if (l == 0) csW[n] = s;
}

// prep 2: w_ih[768][256] f32 -> Wp[n'=3h+g][256] fp16, swizzled
__global__ void __launch_bounds__(256) k_prepWp(const float* __restrict__ w_ih,
                                                _Float16* __restrict__ Wp) {
  int q = blockIdx.x * 256 + threadIdx.x;  // 24576 chunks
  int row = q >> 5, c = q & 31;
  int seg = c >> 3, j = c & 7;
  int srow = (row % 3) * 256 + row / 3;    // gate-interleave permutation
  const float* src = w_ih + (size_t)srow * 256 + c * 8;
  union { half8 v; _Float16 u[8]; } pk;
#pragma unroll
  for (int u = 0; u < 8; ++u) pk.u[u] = f2h(src[u]);
  size_t off = (size_t)row * 512 + seg * 128 + ((j ^ (row & 7)) << 4);
  *(half8*)((char*)Wp + off) = pk.v;
}

// prep 3: GH[64][768] = h @ w_hh^T + b_hh   (exact fp32)
__global__ void __launch_bounds__(256) k_gh(const float* __restrict__ centers,
                                            const float* __restrict__ w_hh,
                                            const float* __restrict__ b_hh,
                                            float* __restrict__ GH) {
  __shared__ __align__(16) float sH[256];
  const int s = blockIdx.x, t = threadIdx.x;
  sH[t] = centers[(size_t)(s >> 2) * 256 + t];
  __syncthreads();
#pragma unroll
  for (int e = 0; e < 3; ++e) {
    int n = e * 256 + t;
    float accv = b_hh[n];
    const float4* w = (const float4*)(w_hh + (size_t)n * 256);
#pragma unroll 8
    for (int k = 0; k < 64; ++k) {
      float4 v = w[k];
      float4 hh = *(const float4*)&sH[k * 4];
      accv += v.x * hh.x + v.y * hh.y + v.z * hh.z + v.w * hh.w;
    }
    GH[(size_t)s * 768 + n] = accv;
  }
}

// ---------------------------------------------------------------------------
// stage 1: X = (A-0.5) @ C   (fp16 MFMA, fp32 accum).
// BM=32, BN=256, BK=64. grid 512, 2 blocks/CU, 256 thr = 4 waves 1Mx4N.
// LDS 72KB: sA dbuf 2x4KB + sB dbuf 2x32KB. Counted-vmcnt pipeline: see
// header comment. FIFO invariant at top of iter k: B(k)[8], A(k+1)[2].
__global__ void __launch_bounds__(256, 2) k_stage1(const float* __restrict__ A,
                                                   const _Float16* __restrict__ Ct,
                                                   _Float16* __restrict__ X) {
  __shared__ __align__(16) _Float16 sA0[32 * 64];   //  4 KB
  __shared__ __align__(16) _Float16 sA1[32 * 64];   //  4 KB
  __shared__ __align__(16) _Float16 sB0[256 * 64];  // 32 KB
  __shared__ __align__(16) _Float16 sB1[256 * 64];  // 32 KB
  const int t = threadIdx.x;
  const int wid = t >> 6, l = t & 63;
  const int lr = l & 15, lk = l >> 4;
  const int m0 = blockIdx.x * 32;

  f32x4 acc[2][4];
#pragma unroll
  for (int i = 0; i < 2; ++i)
#pragma unroll
    for (int j = 0; j < 4; ++j) acc[i][j] = (f32x4){0.f, 0.f, 0.f, 0.f};

  // A staging: thread t -> row ar (0..31), 8-float chunk aj (0..7)
  const int ar = t >> 3, aj = t & 7;
  const float* aptr = A + (size_t)(m0 + ar) * 4096 + aj * 8;
  const int saw = ar * 128 + ((aj ^ (ar & 7)) << 4);

  // B staging: flat = t + 256*i -> row br+32i, chunk bj (src pre-swizzled)
  const int br = t >> 3, bj = t & 7;

  f32x4 aEv[2], aOd[2];

  // ---- prologue: B(0)->sB0 [8 vm]; A(0)->aEv [2 vm]; A(1)->aOd [2 vm];
  //      ds_write A(0)->sA0 (compiler waits A(0): vmcnt(2) -> drains B(0),A(0))
#pragma unroll
  for (int i = 0; i < 8; ++i)
    gload16(Ct + (size_t)(br + 32 * i) * 4096 + bj * 8,
            (char*)sB0 + (wid * 64 + 256 * i) * 16);
  aEv[0] = __builtin_nontemporal_load((const f32x4*)(aptr));
  aEv[1] = __builtin_nontemporal_load((const f32x4*)(aptr + 4));
  aOd[0] = __builtin_nontemporal_load((const f32x4*)(aptr + 64));
  aOd[1] = __builtin_nontemporal_load((const f32x4*)(aptr + 64 + 4));
  {
    union { half8 v; _Float16 u[8]; } pk;
    pk.u[0] = f2h(aEv[0].x - 0.5f); pk.u[1] = f2h(aEv[0].y - 0.5f);
    pk.u[2] = f2h(aEv[0].z - 0.5f); pk.u[3] = f2h(aEv[0].w - 0.5f);
    pk.u[4] = f2h(aEv[1].x - 0.5f); pk.u[5] = f2h(aEv[1].y - 0.5f);
    pk.u[6] = f2h(aEv[1].z - 0.5f); pk.u[7] = f2h(aEv[1].w - 0.5f);
    *(half8*)((char*)sA0 + saw) = pk.v;
  }

  // one pipeline iteration; buffers/regsets are compile-time per call site.
  // aWr holds A(kk+1) (ds_write -> sAn); aLd receives A(kk+2).
  auto body = [&](int kk, const _Float16* sAc, const _Float16* sBc,
                  _Float16* sAn, _Float16* sBn, f32x4* aWr, f32x4* aLd) {
    if (kk == 63) {
      asm volatile("s_waitcnt vmcnt(0)" ::: "memory");
    } else {
      asm volatile("s_waitcnt vmcnt(2)" ::: "memory");  // drain B(kk) exactly
    }
    asm volatile("s_waitcnt lgkmcnt(0)" ::: "memory");
    __builtin_amdgcn_s_barrier();
    __builtin_amdgcn_sched_barrier(0);
    if (kk <= 62) {  // B(kk+1) -> sBn (readers of sBn passed the barrier above)
#pragma unroll
      for (int i = 0; i < 8; ++i)
        gload16(Ct + (size_t)(br + 32 * i) * 4096 + (size_t)(kk + 1) * 64 + bj * 8,
                (char*)sBn + (wid * 64 + 256 * i) * 16);
    }
    if (kk <= 61) {  // A(kk+2) -> aLd (regs freed by iter kk-1's ds_write)
      const float* ap = aptr + (kk + 2) * 64;
      aLd[0] = __builtin_nontemporal_load((const f32x4*)(ap));
      aLd[1] = __builtin_nontemporal_load((const f32x4*)(ap + 4));
    }
    if (kk <= 62) {  // ds_write A(kk+1) -> sAn (compiler-exact vmcnt wait)
      union { half8 v; _Float16 u[8]; } pk;
      pk.u[0] = f2h(aWr[0].x - 0.5f); pk.u[1] = f2h(aWr[0].y - 0.5f);
      pk.u[2] = f2h(aWr[0].z - 0.5f); pk.u[3] = f2h(aWr[0].w - 0.5f);
      pk.u[4] = f2h(aWr[1].x - 0.5f); pk.u[5] = f2h(aWr[1].y - 0.5f);
      pk.u[6] = f2h(aWr[1].z - 0.5f); pk.u[7] = f2h(aWr[1].w - 0.5f);
      *(half8*)((char*)sAn + saw) = pk.v;
    }
    // compute tile kk from sAc, sBc (wave tile 32x64: mi=2, ni=4)
#pragma unroll
    for (int kc = 0; kc < 2; ++kc) {
      const int q = kc * 4 + lk;
      half8 af[2], bf[4];
#pragma unroll
      for (int mi = 0; mi < 2; ++mi) {
        int rl = mi * 16 + lr;
        af[mi] = *(const half8*)((const char*)sAc + rl * 128 + ((q ^ (rl & 7)) << 4));
      }
#pragma unroll
      for (int ni = 0; ni < 4; ++ni) {
        int rb = wid * 64 + ni * 16 + lr;
        bf[ni] = *(const half8*)((const char*)sBc + rb * 128 + ((q ^ (rb & 7)) << 4));
      }
#pragma unroll
      for (int mi = 0; mi < 2; ++mi)
#pragma unroll
        for (int ni = 0; ni < 4; ++ni)
          acc[mi][ni] = __builtin_amdgcn_mfma_f32_16x16x32_f16(af[mi], bf[ni], acc[mi][ni], 0, 0, 0);
    }
  };

  for (int kx = 0; kx < 64; kx += 2) {
    body(kx + 0, sA0, sB0, sA1, sB1, aOd, aEv);
    body(kx + 1, sA1, sB1, sA0, sB0, aEv, aOd);
  }

  // epilogue: X -> fp16 (RNE), pre-swizzled storage
#pragma unroll
  for (int mi = 0; mi < 2; ++mi)
#pragma unroll
    for (int ni = 0; ni < 4; ++ni)
#pragma unroll
      for (int p = 0; p < 4; ++p) {
        int m = m0 + mi * 16 + lk * 4 + p;        // C/D: row=(lane>>4)*4+reg
        int col = wid * 64 + ni * 16 + lr;        //      col=lane&15
        size_t off = (size_t)m * 512 + ((col >> 6) << 7) +
                     ((((col >> 3) & 7) ^ (m & 7)) << 4) + ((col & 7) << 1);
        *(_Float16*)((char*)X + off) = f2h(acc[mi][ni][p]);
      }
}

// ---------------------------------------------------------------------------
// stage 2: GI = X@W (single fp16 pass) + (b_ih + csW) + fused GRU + mean.
// grid 256 (block = batch b), 256 thr, 4 waves 2Mx2N. X panel (32 KB)
// resident in LDS; W tiles (96x256 fp16, 48 KB) staged once per ntile.
// sC (epilogue) aliases the W buffer.
__global__ void __launch_bounds__(256) k_stage2(const _Float16* __restrict__ X,
                                                const _Float16* __restrict__ Wp,
                                                const float* __restrict__ GH,
                                                const float* __restrict__ centers,
                                                const float* __restrict__ b_ih,
                                                const float* __restrict__ csW,
                                                float* __restrict__ out) {
  __shared__ __align__(16) char smem[81920];   // 80 KB
  _Float16* sX = (_Float16*)smem;              // [64][256] fp16 swz : 32 KB
  char*     sW = smem + 32768;                 // [96][256] fp16 swz : 48 KB
  float*    sC = (float*)(smem + 32768);       // [64][100] f32 (aliases sW)
  const int t = threadIdx.x;
  const int wid = t >> 6, l = t & 63;
  const int lr = l & 15, lk = l >> 4;
  const int wm = wid >> 1, wn = wid & 1;
  const int b = blockIdx.x;

  // stage X panel: rows b*64 .. b*64+63 (raw 16B chunks, layout preserved)
#pragma unroll
  for (int i = 0; i < 8; ++i) {
    int flat = t + 256 * i;
    gload16((const char*)X + ((size_t)b * 64 + (flat >> 5)) * 512 +
                (size_t)(flat & 31) * 16,
            (char*)sX + (wid * 64 + 256 * i) * 16);
  }
  __syncthreads();

  for (int nt = 0; nt < 8; ++nt) {
    const int n0 = nt * 96;
    f32x4 acc[2][3];
#pragma unroll
    for (int i = 0; i < 2; ++i)
#pragma unroll
      for (int j = 0; j < 3; ++j) acc[i][j] = (f32x4){0.f, 0.f, 0.f, 0.f};

    // stage W tile 96 x 512B
#pragma unroll
    for (int i = 0; i < 12; ++i) {
      int flat = t + 256 * i;
      gload16((const char*)Wp + (size_t)(n0 + (flat >> 5)) * 512 +
                  (size_t)(flat & 31) * 16,
              sW + (wid * 64 + 256 * i) * 16);
    }
    __syncthreads();  // full drain: W visible
#pragma unroll
    for (int kc = 0; kc < 8; ++kc) {
      const int q = kc * 4 + lk;
      const int seg = (q >> 3) << 7, jj = q & 7;
      half8 af[2];
#pragma unroll
      for (int mi = 0; mi < 2; ++mi) {
        int rl = wm * 32 + mi * 16 + lr;
        af[mi] = *(const half8*)((const char*)sX + rl * 512 + seg + ((jj ^ (rl & 7)) << 4));
      }
#pragma unroll
      for (int ni = 0; ni < 3; ++ni) {
        int rw = wn * 48 + ni * 16 + lr;
        half8 bf = *(const half8*)(sW + rw * 512 + seg + ((jj ^ (rw & 7)) << 4));
#pragma unroll
        for (int mi = 0; mi < 2; ++mi)
          acc[mi][ni] = __builtin_amdgcn_mfma_f32_16x16x32_f16(af[mi], bf, acc[mi][ni], 0, 0, 0);
      }
    }
    __syncthreads();  // all sW reads done before sC alias write
    // acc -> sC (rows = slot s, cols = 3*hl + gate)
#pragma unroll
    for (int mi = 0; mi < 2; ++mi)
#pragma unroll
      for (int ni = 0; ni < 3; ++ni)
#pragma unroll
        for (int p = 0; p < 4; ++p) {
          int row = wm * 32 + mi * 16 + lk * 4 + p;
          int col = wn * 48 + ni * 16 + lr;
          sC[row * 100 + col] = acc[mi][ni][p];
        }
    __syncthreads();
    // fused GRU + level-mean: 16 o x 32 h = 512 items, 2 per thread
#pragma unroll
    for (int ii = 0; ii < 2; ++ii) {
      int item = t + 256 * ii;
      int hl = item & 31, o = item >> 5;
      int h = nt * 32 + hl;
      float hprev = centers[o * 256 + h];
      float bir = b_ih[h] + csW[h];
      float biz = b_ih[256 + h] + csW[256 + h];
      float bin = b_ih[512 + h] + csW[512 + h];
      float sum = 0.f;
#pragma unroll
      for (int j = 0; j < 4; ++j) {
        int s = 4 * o + j;
        float gir = sC[s * 100 + 3 * hl + 0] + bir;
        float giz = sC[s * 100 + 3 * hl + 1] + biz;
        float gin = sC[s * 100 + 3 * hl + 2] + bin;
        float rg = sigmf(gir + GH[s * 768 + h]);
        float zg = sigmf(giz + GH[s * 768 + 256 + h]);
        float ng = tanhf2(gin + rg * GH[s * 768 + 512 + h]);
        sum += (1.f - zg) * ng + zg * hprev;
      }
      out[(size_t)o * 65536 + (size_t)b * 256 + h] = 0.25f * sum;
    }
    __syncthreads();  // sC reads done before next ntile's sW stage (alias)
  }
}

// ---------------------------------------------------------------------------
extern "C" void kernel_launch(void* const* d_in, const int* in_sizes, int n_in,
                              void* d_out, int out_size, void* d_ws, size_t ws_size,
                              hipStream_t stream) {
  (void)in_sizes; (void)n_in; (void)out_size; (void)ws_size;
  const float* attn    = (const float*)d_in[0];  // [256][64][4096]
  const float* centers = (const float*)d_in[1];  // [4096][256]
  const float* w_ih    = (const float*)d_in[2];  // [768][256]
  const float* w_hh    = (const float*)d_in[3];  // [768][256]
  const float* b_ih    = (const float*)d_in[4];  // [768]
  const float* b_hh    = (const float*)d_in[5];  // [768]

  char* ws = (char*)d_ws;
  _Float16* Ct  = (_Float16*)(ws + WS_CT);
  _Float16* Wpp = (_Float16*)(ws + WS_WP);
  float*    GHp = (float*)(ws + WS_GH);
  float*    csp = (float*)(ws + WS_CSP);
  float*    cs  = (float*)(ws + WS_CS);
  float*    csW = (float*)(ws + WS_CSW);
  _Float16* X   = (_Float16*)(ws + WS_X);
  float* out = (float*)d_out;

  hipLaunchKernelGGL(k_transC, dim3(64, 4), dim3(256), 0, stream, centers, Ct);
  hipLaunchKernelGGL(k_csum, dim3(64), dim3(256), 0, stream, centers, csp);
  hipLaunchKernelGGL(k_csum2, dim3(1), dim3(256), 0, stream, csp, cs);
  hipLaunchKernelGGL(k_csumW, dim3(192), dim3(256), 0, stream, w_ih, cs, csW);
  hipLaunchKernelGGL(k_prepWp, dim3(96), dim3(256), 0, stream, w_ih, Wpp);
  hipLaunchKernelGGL(k_gh, dim3(64), dim3(256), 0, stream, centers, w_hh, b_hh, GHp);
  hipLaunchKernelGGL(k_stage1, dim3(512), dim3(256), 0, stream, attn, Ct, X);
  hipLaunchKernelGGL(k_stage2, dim3(256), dim3(256), 0, stream, X, Wpp, GHp, centers, b_ih, csW, out);
}